// Round 8
// baseline (135.225 us; speedup 1.0000x reference)
//
#include <hip/hip_runtime.h>

// ---------------------------------------------------------------------------
// 2-layer TransformerConv factored through the 2-dim feature spaces.
// Round 8: un-fuse the round-7 l1f (60.7us @ 12.9% occupancy, grid=391).
// (a) Edge reduces split into S=8 slices per bucket (3128 blocks, LDS
//     partials, coalesced partial writes, zero global atomics).
// (b) Node projection as its own kernel; weights read via wave-uniform
//     global loads (s_load, scalar pipe) -- no LDS in the 256-dim loop.
// (c) out2_k: partial reduce + skip + log_softmax.
// ---------------------------------------------------------------------------

#define R_LOG2   8
#define R_DSTS   256            // dsts per bucket
#define BE       4096           // edges per partition block
#define MAXNB    512            // supports N <= 131072
#define S_SLICES 8              // edge slices per bucket
#define RSQRT2   0.70710678118654752f

__device__ __forceinline__ int wave_excl_scan(int v, int lane, int& total) {
    int incl = v;
#pragma unroll
    for (int o = 1; o < 64; o <<= 1) {
        int t = __shfl_up(incl, o);
        if (lane >= o) incl += t;
    }
    total = __shfl(incl, 63);
    return incl - v;
}

// 9 reduction coefficients for the layer-1 bilinear attention form:
// q1(d).k1(s) = xd^T M xs + u.xd + w.xs + c   (before 1/16 scale)
__global__ void coeff_k(const float* __restrict__ Wq1, const float* __restrict__ bq1,
                        const float* __restrict__ Wk1, const float* __restrict__ bk1,
                        float* __restrict__ coeff) {
    __shared__ float part[4][9];
    int c = threadIdx.x;  // 256 threads
    float wq0 = Wq1[c], wq1 = Wq1[256 + c];
    float wk0 = Wk1[c], wk1 = Wk1[256 + c];
    float bq = bq1[c], bk = bk1[c];
    float vals[9] = { wq0 * wk0, wq0 * wk1, wq1 * wk0, wq1 * wk1,
                      wq0 * bk,  wq1 * bk,  bq * wk0,  bq * wk1,  bq * bk };
    int lane = c & 63, w = c >> 6;
#pragma unroll
    for (int i = 0; i < 9; ++i) {
        float v = vals[i];
#pragma unroll
        for (int o = 32; o > 0; o >>= 1) v += __shfl_xor(v, o);
        if (lane == 0) part[w][i] = v;
    }
    __syncthreads();
    if (c < 9) coeff[c] = part[0][c] + part[1][c] + part[2][c] + part[3][c];
}

// Per-block bucket histogram -> C[bucket][block].
__global__ __launch_bounds__(256) void count_k(
        const int* __restrict__ dst, int* __restrict__ C,
        int NB, int NBlk, int E) {
    __shared__ int hist[MAXNB];
    int t = threadIdx.x;
    for (int i = t; i < NB; i += 256) hist[i] = 0;
    __syncthreads();
    int base = blockIdx.x * BE;
    int nloc = E - base; if (nloc > BE) nloc = BE;
    int nv = nloc >> 2;
    const int4* d4 = (const int4*)(dst + base);
    for (int i = t; i < nv; i += 256) {
        int4 v = d4[i];
        atomicAdd(&hist[v.x >> R_LOG2], 1);
        atomicAdd(&hist[v.y >> R_LOG2], 1);
        atomicAdd(&hist[v.z >> R_LOG2], 1);
        atomicAdd(&hist[v.w >> R_LOG2], 1);
    }
    for (int i = (nv << 2) + t; i < nloc; i += 256)
        atomicAdd(&hist[dst[base + i] >> R_LOG2], 1);
    __syncthreads();
    for (int b = t; b < NB; b += 256)
        C[(size_t)b * NBlk + blockIdx.x] = hist[b];
}

// Exclusive scan along each bucket row (one wave per row), in-place.
__global__ __launch_bounds__(256) void rowscan_k(
        int* __restrict__ C, int* __restrict__ rowTotal, int NB, int NBlk) {
    int lane = threadIdx.x & 63;
    int row = blockIdx.x * 4 + (threadIdx.x >> 6);
    if (row >= NB) return;
    int carry = 0;
    for (int j0 = 0; j0 < NBlk; j0 += 64) {
        int idx = j0 + lane;
        int v = (idx < NBlk) ? C[(size_t)row * NBlk + idx] : 0;
        int tot, ex = wave_excl_scan(v, lane, tot);
        if (idx < NBlk) C[(size_t)row * NBlk + idx] = ex + carry;
        carry += tot;
    }
    if (lane == 0) rowTotal[row] = carry;
}

// Exclusive scan of per-bucket totals -> bucketBase[0..NB] (one wave).
__global__ __launch_bounds__(64) void bucketscan_k(
        const int* __restrict__ rowTotal, int* __restrict__ bucketBase, int NB) {
    int lane = threadIdx.x;
    int carry = 0;
    for (int j0 = 0; j0 < NB; j0 += 64) {
        int idx = j0 + lane;
        int v = (idx < NB) ? rowTotal[idx] : 0;
        int tot, ex = wave_excl_scan(v, lane, tot);
        if (idx < NB) bucketBase[idx] = ex + carry;
        carry += tot;
    }
    if (lane == 0) bucketBase[NB] = carry;
}

// Locally-sorted scatter: LDS histogram -> in-block exclusive scan -> rank &
// stage in bucket order -> ORDERED coalesced global writes (runs contiguous).
__global__ __launch_bounds__(256) void scatter2_k(
        const int* __restrict__ src, const int* __restrict__ dst,
        const int* __restrict__ C, const int* __restrict__ bucketBase,
        int* __restrict__ recs, int NB, int NBlk, int E) {
    __shared__ int hist[MAXNB];
    __shared__ int lofs[MAXNB];
    __shared__ int gbase[MAXNB];
    __shared__ int stage[BE];
    __shared__ unsigned short sbkt[BE];
    __shared__ int wsum[4];
    int t = threadIdx.x;
    for (int i = t; i < NB; i += 256) hist[i] = 0;
    __syncthreads();

    int blk = blockIdx.x;
    int base = blk * BE;
    int nloc = E - base; if (nloc > BE) nloc = BE;
    int nv = nloc >> 2;
    const int4* d4 = (const int4*)(dst + base);
    const int4* s4 = (const int4*)(src + base);

    // pass 1: local histogram
    for (int i = t; i < nv; i += 256) {
        int4 v = d4[i];
        atomicAdd(&hist[v.x >> R_LOG2], 1);
        atomicAdd(&hist[v.y >> R_LOG2], 1);
        atomicAdd(&hist[v.z >> R_LOG2], 1);
        atomicAdd(&hist[v.w >> R_LOG2], 1);
    }
    for (int i = (nv << 2) + t; i < nloc; i += 256)
        atomicAdd(&hist[dst[base + i] >> R_LOG2], 1);
    __syncthreads();

    // in-block exclusive scan hist -> lofs (2 entries per thread, NB<=512)
    {
        int i0 = 2 * t, i1 = 2 * t + 1;
        int a = (i0 < NB) ? hist[i0] : 0;
        int b = (i1 < NB) ? hist[i1] : 0;
        int s = a + b;
        int lane = t & 63, w = t >> 6;
        int incl = s;
#pragma unroll
        for (int o = 1; o < 64; o <<= 1) {
            int u = __shfl_up(incl, o);
            if (lane >= o) incl += u;
        }
        if (lane == 63) wsum[w] = incl;
        __syncthreads();
        int ex = incl - s;
        for (int j = 0; j < w; ++j) ex += wsum[j];
        if (i0 < NB) lofs[i0] = ex;
        if (i1 < NB) lofs[i1] = ex + a;
    }
    __syncthreads();

    // per-bucket global run start (minus local start), reset hist for ranking
    for (int b = t; b < NB; b += 256) {
        gbase[b] = bucketBase[b] + C[(size_t)b * NBlk + blk] - lofs[b];
        hist[b] = 0;
    }
    __syncthreads();

    // pass 2: rank & stage in bucket-sorted order
    for (int i = t; i < nv; i += 256) {
        int4 dv = d4[i];
        int4 sv = s4[i];
        int d, b, r, p;
        d = dv.x; b = d >> R_LOG2; r = atomicAdd(&hist[b], 1); p = lofs[b] + r;
        stage[p] = sv.x | ((d & (R_DSTS - 1)) << 17); sbkt[p] = (unsigned short)b;
        d = dv.y; b = d >> R_LOG2; r = atomicAdd(&hist[b], 1); p = lofs[b] + r;
        stage[p] = sv.y | ((d & (R_DSTS - 1)) << 17); sbkt[p] = (unsigned short)b;
        d = dv.z; b = d >> R_LOG2; r = atomicAdd(&hist[b], 1); p = lofs[b] + r;
        stage[p] = sv.z | ((d & (R_DSTS - 1)) << 17); sbkt[p] = (unsigned short)b;
        d = dv.w; b = d >> R_LOG2; r = atomicAdd(&hist[b], 1); p = lofs[b] + r;
        stage[p] = sv.w | ((d & (R_DSTS - 1)) << 17); sbkt[p] = (unsigned short)b;
    }
    for (int i = (nv << 2) + t; i < nloc; i += 256) {
        int d = dst[base + i];
        int b = d >> R_LOG2;
        int r = atomicAdd(&hist[b], 1);
        int p = lofs[b] + r;
        stage[p] = src[base + i] | ((d & (R_DSTS - 1)) << 17);
        sbkt[p] = (unsigned short)b;
    }
    __syncthreads();

    // pass 3: ordered write — consecutive i -> consecutive addresses per run
    for (int i = t; i < nloc; i += 256)
        recs[gbase[sbkt[i]] + i] = stage[i];
}

// Layer-1 edge reduce, one of S_SLICES slices of one bucket per block.
// Partials out (coalesced), no global atomics.
__global__ __launch_bounds__(256) void l1r_k(
        const float* __restrict__ x, const float* __restrict__ coeff,
        const int* __restrict__ recs, const int* __restrict__ bucketBase,
        float* __restrict__ part, int N) {
    __shared__ float p0[R_DSTS], p1[R_DSTS], pc[R_DSTS];
    __shared__ float ac[3 * R_DSTS];
    int t = threadIdx.x;
    int bs = blockIdx.x;
    int b = bs / S_SLICES;
    int sl = bs - b * S_SLICES;
    int nbase = b << R_LOG2;
    int rem = N - nbase; if (rem > R_DSTS) rem = R_DSTS;

    ac[t] = 0.f; ac[256 + t] = 0.f; ac[512 + t] = 0.f;
    if (t < rem) {
        float2 xd = ((const float2*)x)[nbase + t];
        float c0 = coeff[0], c1 = coeff[1], c2 = coeff[2], c3 = coeff[3];
        float c4 = coeff[4], c5 = coeff[5], c6 = coeff[6], c7 = coeff[7];
        float c8 = coeff[8];
        p0[t] = c0 * xd.x + c2 * xd.y + c6;
        p1[t] = c1 * xd.x + c3 * xd.y + c7;
        pc[t] = c4 * xd.x + c5 * xd.y + c8;
    }
    __syncthreads();

    int eb = bucketBase[b], ee = bucketBase[b + 1];
    int len = (ee - eb + S_SLICES - 1) / S_SLICES;
    int lo = eb + sl * len;
    int hi = lo + len; if (hi > ee) hi = ee;
    for (int i = lo + t; i < hi; i += 256) {
        int rec = recs[i];
        int s = rec & 0x1FFFF;
        int dl = (rec >> 17) & (R_DSTS - 1);
        float2 xs = ((const float2*)x)[s];
        float w = __expf((p0[dl] * xs.x + p1[dl] * xs.y + pc[dl]) * 0.0625f);
        atomicAdd(&ac[dl], w);
        atomicAdd(&ac[256 + dl], w * xs.x);
        atomicAdd(&ac[512 + dl], w * xs.y);
    }
    __syncthreads();

    float* dp = part + (size_t)bs * (3 * R_DSTS);
    dp[t] = ac[t];
    dp[256 + t] = ac[256 + t];
    dp[512 + t] = ac[512 + t];
}

// Per node: reduce S_SLICES partials, reconstruct 256-dim h = relu(layer1)
// in registers, project to q2/kv2/hs2. Weights read via wave-uniform global
// loads (scalar pipe) -- no LDS.
__global__ __launch_bounds__(256) void node_k(
        const float* __restrict__ x, const float* __restrict__ part,
        const float* __restrict__ Wv1, const float* __restrict__ bv1,
        const float* __restrict__ Ws1, const float* __restrict__ bs1,
        const float* __restrict__ Wq2, const float* __restrict__ bq2,
        const float* __restrict__ Wk2, const float* __restrict__ bk2,
        const float* __restrict__ Wv2, const float* __restrict__ bv2,
        const float* __restrict__ Ws2, const float* __restrict__ bs2,
        float* __restrict__ q2, float4* __restrict__ kv2,
        float* __restrict__ hs2, int N) {
    int t = threadIdx.x;
    int b = blockIdx.x;
    int n = (b << R_LOG2) + t;
    if (n >= N) return;

    const float* pp = part + (size_t)b * S_SLICES * (3 * R_DSTS);
    float s = 0.f, sx0 = 0.f, sx1 = 0.f;
#pragma unroll
    for (int sl = 0; sl < S_SLICES; ++sl) {
        s   += pp[sl * 768 + t];
        sx0 += pp[sl * 768 + 256 + t];
        sx1 += pp[sl * 768 + 512 + t];
    }

    float a0 = 0.f, a1 = 0.f, he = 0.f;
    if (s > 0.f) {
        float inv = 1.0f / s;
        a0 = sx0 * inv; a1 = sx1 * inv; he = 1.f;
    }
    float2 xd = ((const float2*)x)[n];

    float acc0 = 0.f, acc1 = 0.f, acc2 = 0.f, acc3 = 0.f;
    float acc4 = 0.f, acc5 = 0.f, acc6 = 0.f, acc7 = 0.f;
#pragma unroll 8
    for (int c = 0; c < 256; ++c) {
        // all weight addresses are wave-uniform -> scalar loads
        float h = a0 * Wv1[c] + a1 * Wv1[256 + c]
                + xd.x * Ws1[c] + xd.y * Ws1[256 + c]
                + he * bv1[c] + bs1[c];
        h = fmaxf(h, 0.f);
        acc0 += h * Wq2[2 * c];
        acc1 += h * Wq2[2 * c + 1];
        acc2 += h * Wk2[2 * c];
        acc3 += h * Wk2[2 * c + 1];
        acc4 += h * Wv2[2 * c];
        acc5 += h * Wv2[2 * c + 1];
        acc6 += h * Ws2[2 * c];
        acc7 += h * Ws2[2 * c + 1];
    }
    ((float2*)q2)[n]  = make_float2(acc0 + bq2[0], acc1 + bq2[1]);
    kv2[n] = make_float4(acc2 + bk2[0], acc3 + bk2[1],   // k2
                         acc4 + bv2[0], acc5 + bv2[1]);  // v2
    ((float2*)hs2)[n] = make_float2(acc6 + bs2[0], acc7 + bs2[1]);
}

// Layer-2 edge reduce (sliced), partials out.
__global__ __launch_bounds__(256) void l2r_k(
        const float* __restrict__ q2, const float4* __restrict__ kv2,
        const int* __restrict__ recs, const int* __restrict__ bucketBase,
        float* __restrict__ part, int N) {
    __shared__ float qx[R_DSTS], qy[R_DSTS];
    __shared__ float ac[3 * R_DSTS];
    int t = threadIdx.x;
    int bs = blockIdx.x;
    int b = bs / S_SLICES;
    int sl = bs - b * S_SLICES;
    int nbase = b << R_LOG2;
    int rem = N - nbase; if (rem > R_DSTS) rem = R_DSTS;

    ac[t] = 0.f; ac[256 + t] = 0.f; ac[512 + t] = 0.f;
    if (t < rem) {
        float2 q = ((const float2*)q2)[nbase + t];
        qx[t] = q.x * RSQRT2;
        qy[t] = q.y * RSQRT2;
    }
    __syncthreads();

    int eb = bucketBase[b], ee = bucketBase[b + 1];
    int len = (ee - eb + S_SLICES - 1) / S_SLICES;
    int lo = eb + sl * len;
    int hi = lo + len; if (hi > ee) hi = ee;
    for (int i = lo + t; i < hi; i += 256) {
        int rec = recs[i];
        int s = rec & 0x1FFFF;
        int dl = (rec >> 17) & (R_DSTS - 1);
        float4 kv = kv2[s];
        float w = __expf(qx[dl] * kv.x + qy[dl] * kv.y);
        atomicAdd(&ac[dl], w);
        atomicAdd(&ac[256 + dl], w * kv.z);
        atomicAdd(&ac[512 + dl], w * kv.w);
    }
    __syncthreads();

    float* dp = part + (size_t)bs * (3 * R_DSTS);
    dp[t] = ac[t];
    dp[256 + t] = ac[256 + t];
    dp[512 + t] = ac[512 + t];
}

// Reduce layer-2 partials + skip + closed-form 2-class log_softmax.
__global__ __launch_bounds__(256) void out2_k(
        const float* __restrict__ part, const float* __restrict__ hs2,
        float* __restrict__ out, int N) {
    int t = threadIdx.x;
    int b = blockIdx.x;
    int n = (b << R_LOG2) + t;
    if (n >= N) return;

    const float* pp = part + (size_t)b * S_SLICES * (3 * R_DSTS);
    float s = 0.f, sv0 = 0.f, sv1 = 0.f;
#pragma unroll
    for (int sl = 0; sl < S_SLICES; ++sl) {
        s   += pp[sl * 768 + t];
        sv0 += pp[sl * 768 + 256 + t];
        sv1 += pp[sl * 768 + 512 + t];
    }
    float g0 = 0.f, g1 = 0.f;
    if (s > 0.f) {
        float inv = 1.0f / s;
        g0 = sv0 * inv; g1 = sv1 * inv;
    }
    float2 hs = ((const float2*)hs2)[n];
    float o0 = g0 + hs.x;
    float o1 = g1 + hs.y;
    float mx = fmaxf(o0, o1), mn = fminf(o0, o1);
    float lse = mx + log1pf(__expf(mn - mx));
    ((float2*)out)[n] = make_float2(o0 - lse, o1 - lse);
}

extern "C" void kernel_launch(void* const* d_in, const int* in_sizes, int n_in,
                              void* d_out, int out_size, void* d_ws, size_t ws_size,
                              hipStream_t stream) {
    const float* x   = (const float*)d_in[0];
    const int*   ei  = (const int*)d_in[1];
    const float* Wq1 = (const float*)d_in[2];
    const float* bq1 = (const float*)d_in[3];
    const float* Wk1 = (const float*)d_in[4];
    const float* bk1 = (const float*)d_in[5];
    const float* Wv1 = (const float*)d_in[6];
    const float* bv1 = (const float*)d_in[7];
    const float* Ws1 = (const float*)d_in[8];
    const float* bs1 = (const float*)d_in[9];
    const float* Wq2 = (const float*)d_in[10];
    const float* bq2 = (const float*)d_in[11];
    const float* Wk2 = (const float*)d_in[12];
    const float* bk2 = (const float*)d_in[13];
    const float* Wv2 = (const float*)d_in[14];
    const float* bv2 = (const float*)d_in[15];
    const float* Ws2 = (const float*)d_in[16];
    const float* bs2 = (const float*)d_in[17];

    const int N = in_sizes[0] / 2;
    const int E = in_sizes[1] / 2;
    const int* src = ei;
    const int* dst = ei + E;

    const int NB   = (N + R_DSTS - 1) >> R_LOG2;     // 391
    const int NBlk = (E + BE - 1) / BE;              // 391

    // workspace layout (4-byte units)
    float* ws = (float*)d_ws;
    size_t off = 0;
    float* coeff      = ws + off;            off += 16;
    int*   bucketBase = (int*)(ws + off);    off += (size_t)NB + 1;
    int*   rowTotal   = (int*)(ws + off);    off += NB;
    int*   C          = (int*)(ws + off);    off += (size_t)NB * NBlk;
    int*   recs       = (int*)(ws + off);    off += E;
    off = (off + 3) & ~(size_t)3;            // 16B align
    float* part       = ws + off;            off += (size_t)NB * S_SLICES * 3 * R_DSTS;
    float4* kv2       = (float4*)(ws + off); off += 4 * (size_t)N;
    float* q2         = ws + off;            off += 2 * (size_t)N;
    float* hs2        = ws + off;            off += 2 * (size_t)N;

    coeff_k<<<1, 256, 0, stream>>>(Wq1, bq1, Wk1, bk1, coeff);
    count_k<<<NBlk, 256, 0, stream>>>(dst, C, NB, NBlk, E);
    rowscan_k<<<(NB + 3) / 4, 256, 0, stream>>>(C, rowTotal, NB, NBlk);
    bucketscan_k<<<1, 64, 0, stream>>>(rowTotal, bucketBase, NB);
    scatter2_k<<<NBlk, 256, 0, stream>>>(src, dst, C, bucketBase, recs, NB, NBlk, E);
    l1r_k<<<NB * S_SLICES, 256, 0, stream>>>(x, coeff, recs, bucketBase, part, N);
    node_k<<<NB, 256, 0, stream>>>(x, part, Wv1, bv1, Ws1, bs1,
                                   Wq2, bq2, Wk2, bk2, Wv2, bv2, Ws2, bs2,
                                   q2, kv2, hs2, N);
    l2r_k<<<NB * S_SLICES, 256, 0, stream>>>(q2, kv2, recs, bucketBase, part, N);
    out2_k<<<NB, 256, 0, stream>>>(part, hs2, (float*)d_out, N);
}

// Round 9
// 124.995 us; speedup vs baseline: 1.0818x; 1.0818x over previous
//
#include <hip/hip_runtime.h>

// ---------------------------------------------------------------------------
// 2-layer TransformerConv factored through the 2-dim feature spaces.
// Round 9: fix node_k (41us @ 15% occupancy, latency-bound serial weight
// loads). proj_k: 8-lane group per node (3125 blocks), weights in LDS read
// as broadcast-conflict-free ds_read_b128 (14 instr/node invariant), slice
// partials folded into the group via width-8 shfl reduce. Same grouping for
// the output kernel. Partition + sliced edge reduces unchanged.
// ---------------------------------------------------------------------------

#define R_LOG2   8
#define R_DSTS   256            // dsts per bucket
#define BE       4096           // edges per partition block
#define MAXNB    512            // supports N <= 131072
#define S_SLICES 8              // edge slices per bucket
#define RSQRT2   0.70710678118654752f

__device__ __forceinline__ int wave_excl_scan(int v, int lane, int& total) {
    int incl = v;
#pragma unroll
    for (int o = 1; o < 64; o <<= 1) {
        int t = __shfl_up(incl, o);
        if (lane >= o) incl += t;
    }
    total = __shfl(incl, 63);
    return incl - v;
}

// 9 reduction coefficients for the layer-1 bilinear attention form:
// q1(d).k1(s) = xd^T M xs + u.xd + w.xs + c   (before 1/16 scale)
__global__ void coeff_k(const float* __restrict__ Wq1, const float* __restrict__ bq1,
                        const float* __restrict__ Wk1, const float* __restrict__ bk1,
                        float* __restrict__ coeff) {
    __shared__ float part[4][9];
    int c = threadIdx.x;  // 256 threads
    float wq0 = Wq1[c], wq1 = Wq1[256 + c];
    float wk0 = Wk1[c], wk1 = Wk1[256 + c];
    float bq = bq1[c], bk = bk1[c];
    float vals[9] = { wq0 * wk0, wq0 * wk1, wq1 * wk0, wq1 * wk1,
                      wq0 * bk,  wq1 * bk,  bq * wk0,  bq * wk1,  bq * bk };
    int lane = c & 63, w = c >> 6;
#pragma unroll
    for (int i = 0; i < 9; ++i) {
        float v = vals[i];
#pragma unroll
        for (int o = 32; o > 0; o >>= 1) v += __shfl_xor(v, o);
        if (lane == 0) part[w][i] = v;
    }
    __syncthreads();
    if (c < 9) coeff[c] = part[0][c] + part[1][c] + part[2][c] + part[3][c];
}

// Per-block bucket histogram -> C[bucket][block].
__global__ __launch_bounds__(256) void count_k(
        const int* __restrict__ dst, int* __restrict__ C,
        int NB, int NBlk, int E) {
    __shared__ int hist[MAXNB];
    int t = threadIdx.x;
    for (int i = t; i < NB; i += 256) hist[i] = 0;
    __syncthreads();
    int base = blockIdx.x * BE;
    int nloc = E - base; if (nloc > BE) nloc = BE;
    int nv = nloc >> 2;
    const int4* d4 = (const int4*)(dst + base);
    for (int i = t; i < nv; i += 256) {
        int4 v = d4[i];
        atomicAdd(&hist[v.x >> R_LOG2], 1);
        atomicAdd(&hist[v.y >> R_LOG2], 1);
        atomicAdd(&hist[v.z >> R_LOG2], 1);
        atomicAdd(&hist[v.w >> R_LOG2], 1);
    }
    for (int i = (nv << 2) + t; i < nloc; i += 256)
        atomicAdd(&hist[dst[base + i] >> R_LOG2], 1);
    __syncthreads();
    for (int b = t; b < NB; b += 256)
        C[(size_t)b * NBlk + blockIdx.x] = hist[b];
}

// Exclusive scan along each bucket row (one wave per row), in-place.
__global__ __launch_bounds__(256) void rowscan_k(
        int* __restrict__ C, int* __restrict__ rowTotal, int NB, int NBlk) {
    int lane = threadIdx.x & 63;
    int row = blockIdx.x * 4 + (threadIdx.x >> 6);
    if (row >= NB) return;
    int carry = 0;
    for (int j0 = 0; j0 < NBlk; j0 += 64) {
        int idx = j0 + lane;
        int v = (idx < NBlk) ? C[(size_t)row * NBlk + idx] : 0;
        int tot, ex = wave_excl_scan(v, lane, tot);
        if (idx < NBlk) C[(size_t)row * NBlk + idx] = ex + carry;
        carry += tot;
    }
    if (lane == 0) rowTotal[row] = carry;
}

// Exclusive scan of per-bucket totals -> bucketBase[0..NB] (one wave).
__global__ __launch_bounds__(64) void bucketscan_k(
        const int* __restrict__ rowTotal, int* __restrict__ bucketBase, int NB) {
    int lane = threadIdx.x;
    int carry = 0;
    for (int j0 = 0; j0 < NB; j0 += 64) {
        int idx = j0 + lane;
        int v = (idx < NB) ? rowTotal[idx] : 0;
        int tot, ex = wave_excl_scan(v, lane, tot);
        if (idx < NB) bucketBase[idx] = ex + carry;
        carry += tot;
    }
    if (lane == 0) bucketBase[NB] = carry;
}

// Locally-sorted scatter: LDS histogram -> in-block exclusive scan -> rank &
// stage in bucket order -> ORDERED coalesced global writes (runs contiguous).
__global__ __launch_bounds__(256) void scatter2_k(
        const int* __restrict__ src, const int* __restrict__ dst,
        const int* __restrict__ C, const int* __restrict__ bucketBase,
        int* __restrict__ recs, int NB, int NBlk, int E) {
    __shared__ int hist[MAXNB];
    __shared__ int lofs[MAXNB];
    __shared__ int gbase[MAXNB];
    __shared__ int stage[BE];
    __shared__ unsigned short sbkt[BE];
    __shared__ int wsum[4];
    int t = threadIdx.x;
    for (int i = t; i < NB; i += 256) hist[i] = 0;
    __syncthreads();

    int blk = blockIdx.x;
    int base = blk * BE;
    int nloc = E - base; if (nloc > BE) nloc = BE;
    int nv = nloc >> 2;
    const int4* d4 = (const int4*)(dst + base);
    const int4* s4 = (const int4*)(src + base);

    // pass 1: local histogram
    for (int i = t; i < nv; i += 256) {
        int4 v = d4[i];
        atomicAdd(&hist[v.x >> R_LOG2], 1);
        atomicAdd(&hist[v.y >> R_LOG2], 1);
        atomicAdd(&hist[v.z >> R_LOG2], 1);
        atomicAdd(&hist[v.w >> R_LOG2], 1);
    }
    for (int i = (nv << 2) + t; i < nloc; i += 256)
        atomicAdd(&hist[dst[base + i] >> R_LOG2], 1);
    __syncthreads();

    // in-block exclusive scan hist -> lofs (2 entries per thread, NB<=512)
    {
        int i0 = 2 * t, i1 = 2 * t + 1;
        int a = (i0 < NB) ? hist[i0] : 0;
        int b = (i1 < NB) ? hist[i1] : 0;
        int s = a + b;
        int lane = t & 63, w = t >> 6;
        int incl = s;
#pragma unroll
        for (int o = 1; o < 64; o <<= 1) {
            int u = __shfl_up(incl, o);
            if (lane >= o) incl += u;
        }
        if (lane == 63) wsum[w] = incl;
        __syncthreads();
        int ex = incl - s;
        for (int j = 0; j < w; ++j) ex += wsum[j];
        if (i0 < NB) lofs[i0] = ex;
        if (i1 < NB) lofs[i1] = ex + a;
    }
    __syncthreads();

    // per-bucket global run start (minus local start), reset hist for ranking
    for (int b = t; b < NB; b += 256) {
        gbase[b] = bucketBase[b] + C[(size_t)b * NBlk + blk] - lofs[b];
        hist[b] = 0;
    }
    __syncthreads();

    // pass 2: rank & stage in bucket-sorted order
    for (int i = t; i < nv; i += 256) {
        int4 dv = d4[i];
        int4 sv = s4[i];
        int d, b, r, p;
        d = dv.x; b = d >> R_LOG2; r = atomicAdd(&hist[b], 1); p = lofs[b] + r;
        stage[p] = sv.x | ((d & (R_DSTS - 1)) << 17); sbkt[p] = (unsigned short)b;
        d = dv.y; b = d >> R_LOG2; r = atomicAdd(&hist[b], 1); p = lofs[b] + r;
        stage[p] = sv.y | ((d & (R_DSTS - 1)) << 17); sbkt[p] = (unsigned short)b;
        d = dv.z; b = d >> R_LOG2; r = atomicAdd(&hist[b], 1); p = lofs[b] + r;
        stage[p] = sv.z | ((d & (R_DSTS - 1)) << 17); sbkt[p] = (unsigned short)b;
        d = dv.w; b = d >> R_LOG2; r = atomicAdd(&hist[b], 1); p = lofs[b] + r;
        stage[p] = sv.w | ((d & (R_DSTS - 1)) << 17); sbkt[p] = (unsigned short)b;
    }
    for (int i = (nv << 2) + t; i < nloc; i += 256) {
        int d = dst[base + i];
        int b = d >> R_LOG2;
        int r = atomicAdd(&hist[b], 1);
        int p = lofs[b] + r;
        stage[p] = src[base + i] | ((d & (R_DSTS - 1)) << 17);
        sbkt[p] = (unsigned short)b;
    }
    __syncthreads();

    // pass 3: ordered write — consecutive i -> consecutive addresses per run
    for (int i = t; i < nloc; i += 256)
        recs[gbase[sbkt[i]] + i] = stage[i];
}

// Layer-1 edge reduce, one of S_SLICES slices of one bucket per block.
// Partials out (coalesced), no global atomics.
__global__ __launch_bounds__(256) void l1r_k(
        const float* __restrict__ x, const float* __restrict__ coeff,
        const int* __restrict__ recs, const int* __restrict__ bucketBase,
        float* __restrict__ part, int N) {
    __shared__ float p0[R_DSTS], p1[R_DSTS], pc[R_DSTS];
    __shared__ float ac[3 * R_DSTS];
    int t = threadIdx.x;
    int bs = blockIdx.x;
    int b = bs / S_SLICES;
    int sl = bs - b * S_SLICES;
    int nbase = b << R_LOG2;
    int rem = N - nbase; if (rem > R_DSTS) rem = R_DSTS;

    ac[t] = 0.f; ac[256 + t] = 0.f; ac[512 + t] = 0.f;
    if (t < rem) {
        float2 xd = ((const float2*)x)[nbase + t];
        float c0 = coeff[0], c1 = coeff[1], c2 = coeff[2], c3 = coeff[3];
        float c4 = coeff[4], c5 = coeff[5], c6 = coeff[6], c7 = coeff[7];
        float c8 = coeff[8];
        p0[t] = c0 * xd.x + c2 * xd.y + c6;
        p1[t] = c1 * xd.x + c3 * xd.y + c7;
        pc[t] = c4 * xd.x + c5 * xd.y + c8;
    }
    __syncthreads();

    int eb = bucketBase[b], ee = bucketBase[b + 1];
    int len = (ee - eb + S_SLICES - 1) / S_SLICES;
    int lo = eb + sl * len;
    int hi = lo + len; if (hi > ee) hi = ee;
    for (int i = lo + t; i < hi; i += 256) {
        int rec = recs[i];
        int s = rec & 0x1FFFF;
        int dl = (rec >> 17) & (R_DSTS - 1);
        float2 xs = ((const float2*)x)[s];
        float w = __expf((p0[dl] * xs.x + p1[dl] * xs.y + pc[dl]) * 0.0625f);
        atomicAdd(&ac[dl], w);
        atomicAdd(&ac[256 + dl], w * xs.x);
        atomicAdd(&ac[512 + dl], w * xs.y);
    }
    __syncthreads();

    float* dp = part + (size_t)bs * (3 * R_DSTS);
    dp[t] = ac[t];
    dp[256 + t] = ac[256 + t];
    dp[512 + t] = ac[512 + t];
}

// Node projection: 8-lane group per node. Slice partials reduced via
// width-8 shuffles; weights in LDS, read as broadcast ds_read_b128
// (channels c = g*4 + 32*j -> 128B contiguous per wave, conflict-free).
__global__ __launch_bounds__(256) void proj_k(
        const float* __restrict__ x, const float* __restrict__ part,
        const float* __restrict__ Wv1, const float* __restrict__ bv1,
        const float* __restrict__ Ws1, const float* __restrict__ bs1,
        const float* __restrict__ Wq2, const float* __restrict__ bq2,
        const float* __restrict__ Wk2, const float* __restrict__ bk2,
        const float* __restrict__ Wv2, const float* __restrict__ bv2,
        const float* __restrict__ Ws2, const float* __restrict__ bs2,
        float* __restrict__ q2, float4* __restrict__ kv2,
        float* __restrict__ hs2, int N) {
    __shared__ float sW[14][256];
    int t = threadIdx.x;
    sW[0][t]  = Wv1[t];
    sW[1][t]  = Wv1[256 + t];
    sW[2][t]  = Ws1[t];
    sW[3][t]  = Ws1[256 + t];
    sW[4][t]  = bv1[t];
    sW[5][t]  = bs1[t];
    sW[6][t]  = Wq2[2 * t];
    sW[7][t]  = Wq2[2 * t + 1];
    sW[8][t]  = Wk2[2 * t];
    sW[9][t]  = Wk2[2 * t + 1];
    sW[10][t] = Wv2[2 * t];
    sW[11][t] = Wv2[2 * t + 1];
    sW[12][t] = Ws2[2 * t];
    sW[13][t] = Ws2[2 * t + 1];
    __syncthreads();

    int g = t & 7;
    int n = blockIdx.x * 32 + (t >> 3);
    if (n >= N) return;
    int b = n >> R_LOG2, idx = n & (R_DSTS - 1);

    // slice-g partial, then width-8 xor reduce (all lanes get the sums)
    const float* pp = part + ((size_t)(b * S_SLICES + g)) * (3 * R_DSTS) + idx;
    float s = pp[0], sx0 = pp[256], sx1 = pp[512];
#pragma unroll
    for (int m = 1; m < 8; m <<= 1) {
        s   += __shfl_xor(s, m);
        sx0 += __shfl_xor(sx0, m);
        sx1 += __shfl_xor(sx1, m);
    }
    float a0 = 0.f, a1 = 0.f, he = 0.f;
    if (s > 0.f) {
        float inv = 1.0f / s;
        a0 = sx0 * inv; a1 = sx1 * inv; he = 1.f;
    }
    float2 xd = ((const float2*)x)[n];

    float acc0 = 0.f, acc1 = 0.f, acc2 = 0.f, acc3 = 0.f;
    float acc4 = 0.f, acc5 = 0.f, acc6 = 0.f, acc7 = 0.f;
#pragma unroll
    for (int j = 0; j < 8; ++j) {
        int ci = g + 8 * j;  // float4 index; c = 4*ci
        float4 w0 = ((const float4*)sW[0])[ci];
        float4 w1 = ((const float4*)sW[1])[ci];
        float4 w2 = ((const float4*)sW[2])[ci];
        float4 w3 = ((const float4*)sW[3])[ci];
        float4 w4 = ((const float4*)sW[4])[ci];
        float4 w5 = ((const float4*)sW[5])[ci];
        float4 h;
        h.x = fmaxf(a0 * w0.x + a1 * w1.x + xd.x * w2.x + xd.y * w3.x + he * w4.x + w5.x, 0.f);
        h.y = fmaxf(a0 * w0.y + a1 * w1.y + xd.x * w2.y + xd.y * w3.y + he * w4.y + w5.y, 0.f);
        h.z = fmaxf(a0 * w0.z + a1 * w1.z + xd.x * w2.z + xd.y * w3.z + he * w4.z + w5.z, 0.f);
        h.w = fmaxf(a0 * w0.w + a1 * w1.w + xd.x * w2.w + xd.y * w3.w + he * w4.w + w5.w, 0.f);
        float4 u;
        u = ((const float4*)sW[6])[ci];  acc0 += h.x*u.x + h.y*u.y + h.z*u.z + h.w*u.w;
        u = ((const float4*)sW[7])[ci];  acc1 += h.x*u.x + h.y*u.y + h.z*u.z + h.w*u.w;
        u = ((const float4*)sW[8])[ci];  acc2 += h.x*u.x + h.y*u.y + h.z*u.z + h.w*u.w;
        u = ((const float4*)sW[9])[ci];  acc3 += h.x*u.x + h.y*u.y + h.z*u.z + h.w*u.w;
        u = ((const float4*)sW[10])[ci]; acc4 += h.x*u.x + h.y*u.y + h.z*u.z + h.w*u.w;
        u = ((const float4*)sW[11])[ci]; acc5 += h.x*u.x + h.y*u.y + h.z*u.z + h.w*u.w;
        u = ((const float4*)sW[12])[ci]; acc6 += h.x*u.x + h.y*u.y + h.z*u.z + h.w*u.w;
        u = ((const float4*)sW[13])[ci]; acc7 += h.x*u.x + h.y*u.y + h.z*u.z + h.w*u.w;
    }
#pragma unroll
    for (int m = 1; m < 8; m <<= 1) {
        acc0 += __shfl_xor(acc0, m);
        acc1 += __shfl_xor(acc1, m);
        acc2 += __shfl_xor(acc2, m);
        acc3 += __shfl_xor(acc3, m);
        acc4 += __shfl_xor(acc4, m);
        acc5 += __shfl_xor(acc5, m);
        acc6 += __shfl_xor(acc6, m);
        acc7 += __shfl_xor(acc7, m);
    }
    if (g == 0) {
        ((float2*)q2)[n]  = make_float2(acc0 + bq2[0], acc1 + bq2[1]);
        kv2[n] = make_float4(acc2 + bk2[0], acc3 + bk2[1],
                             acc4 + bv2[0], acc5 + bv2[1]);
        ((float2*)hs2)[n] = make_float2(acc6 + bs2[0], acc7 + bs2[1]);
    }
}

// Layer-2 edge reduce (sliced), partials out.
__global__ __launch_bounds__(256) void l2r_k(
        const float* __restrict__ q2, const float4* __restrict__ kv2,
        const int* __restrict__ recs, const int* __restrict__ bucketBase,
        float* __restrict__ part, int N) {
    __shared__ float qx[R_DSTS], qy[R_DSTS];
    __shared__ float ac[3 * R_DSTS];
    int t = threadIdx.x;
    int bs = blockIdx.x;
    int b = bs / S_SLICES;
    int sl = bs - b * S_SLICES;
    int nbase = b << R_LOG2;
    int rem = N - nbase; if (rem > R_DSTS) rem = R_DSTS;

    ac[t] = 0.f; ac[256 + t] = 0.f; ac[512 + t] = 0.f;
    if (t < rem) {
        float2 q = ((const float2*)q2)[nbase + t];
        qx[t] = q.x * RSQRT2;
        qy[t] = q.y * RSQRT2;
    }
    __syncthreads();

    int eb = bucketBase[b], ee = bucketBase[b + 1];
    int len = (ee - eb + S_SLICES - 1) / S_SLICES;
    int lo = eb + sl * len;
    int hi = lo + len; if (hi > ee) hi = ee;
    for (int i = lo + t; i < hi; i += 256) {
        int rec = recs[i];
        int s = rec & 0x1FFFF;
        int dl = (rec >> 17) & (R_DSTS - 1);
        float4 kv = kv2[s];
        float w = __expf(qx[dl] * kv.x + qy[dl] * kv.y);
        atomicAdd(&ac[dl], w);
        atomicAdd(&ac[256 + dl], w * kv.z);
        atomicAdd(&ac[512 + dl], w * kv.w);
    }
    __syncthreads();

    float* dp = part + (size_t)bs * (3 * R_DSTS);
    dp[t] = ac[t];
    dp[256 + t] = ac[256 + t];
    dp[512 + t] = ac[512 + t];
}

// Output: 8-lane group per node reduces layer-2 slice partials, then skip +
// closed-form 2-class log_softmax.
__global__ __launch_bounds__(256) void out2x_k(
        const float* __restrict__ part, const float* __restrict__ hs2,
        float* __restrict__ out, int N) {
    int t = threadIdx.x;
    int g = t & 7;
    int n = blockIdx.x * 32 + (t >> 3);
    if (n >= N) return;
    int b = n >> R_LOG2, idx = n & (R_DSTS - 1);

    const float* pp = part + ((size_t)(b * S_SLICES + g)) * (3 * R_DSTS) + idx;
    float s = pp[0], sv0 = pp[256], sv1 = pp[512];
#pragma unroll
    for (int m = 1; m < 8; m <<= 1) {
        s   += __shfl_xor(s, m);
        sv0 += __shfl_xor(sv0, m);
        sv1 += __shfl_xor(sv1, m);
    }
    if (g != 0) return;

    float g0 = 0.f, g1 = 0.f;
    if (s > 0.f) {
        float inv = 1.0f / s;
        g0 = sv0 * inv; g1 = sv1 * inv;
    }
    float2 hs = ((const float2*)hs2)[n];
    float o0 = g0 + hs.x;
    float o1 = g1 + hs.y;
    float mx = fmaxf(o0, o1), mn = fminf(o0, o1);
    float lse = mx + log1pf(__expf(mn - mx));
    ((float2*)out)[n] = make_float2(o0 - lse, o1 - lse);
}

extern "C" void kernel_launch(void* const* d_in, const int* in_sizes, int n_in,
                              void* d_out, int out_size, void* d_ws, size_t ws_size,
                              hipStream_t stream) {
    const float* x   = (const float*)d_in[0];
    const int*   ei  = (const int*)d_in[1];
    const float* Wq1 = (const float*)d_in[2];
    const float* bq1 = (const float*)d_in[3];
    const float* Wk1 = (const float*)d_in[4];
    const float* bk1 = (const float*)d_in[5];
    const float* Wv1 = (const float*)d_in[6];
    const float* bv1 = (const float*)d_in[7];
    const float* Ws1 = (const float*)d_in[8];
    const float* bs1 = (const float*)d_in[9];
    const float* Wq2 = (const float*)d_in[10];
    const float* bq2 = (const float*)d_in[11];
    const float* Wk2 = (const float*)d_in[12];
    const float* bk2 = (const float*)d_in[13];
    const float* Wv2 = (const float*)d_in[14];
    const float* bv2 = (const float*)d_in[15];
    const float* Ws2 = (const float*)d_in[16];
    const float* bs2 = (const float*)d_in[17];

    const int N = in_sizes[0] / 2;
    const int E = in_sizes[1] / 2;
    const int* src = ei;
    const int* dst = ei + E;

    const int NB   = (N + R_DSTS - 1) >> R_LOG2;     // 391
    const int NBlk = (E + BE - 1) / BE;              // 391

    // workspace layout (4-byte units)
    float* ws = (float*)d_ws;
    size_t off = 0;
    float* coeff      = ws + off;            off += 16;
    int*   bucketBase = (int*)(ws + off);    off += (size_t)NB + 1;
    int*   rowTotal   = (int*)(ws + off);    off += NB;
    int*   C          = (int*)(ws + off);    off += (size_t)NB * NBlk;
    int*   recs       = (int*)(ws + off);    off += E;
    off = (off + 3) & ~(size_t)3;            // 16B align
    float* part       = ws + off;            off += (size_t)NB * S_SLICES * 3 * R_DSTS;
    float4* kv2       = (float4*)(ws + off); off += 4 * (size_t)N;
    float* q2         = ws + off;            off += 2 * (size_t)N;
    float* hs2        = ws + off;            off += 2 * (size_t)N;

    const int gP = (N + 31) / 32;   // 8-lane-group kernels: 32 nodes/block

    coeff_k<<<1, 256, 0, stream>>>(Wq1, bq1, Wk1, bk1, coeff);
    count_k<<<NBlk, 256, 0, stream>>>(dst, C, NB, NBlk, E);
    rowscan_k<<<(NB + 3) / 4, 256, 0, stream>>>(C, rowTotal, NB, NBlk);
    bucketscan_k<<<1, 64, 0, stream>>>(rowTotal, bucketBase, NB);
    scatter2_k<<<NBlk, 256, 0, stream>>>(src, dst, C, bucketBase, recs, NB, NBlk, E);
    l1r_k<<<NB * S_SLICES, 256, 0, stream>>>(x, coeff, recs, bucketBase, part, N);
    proj_k<<<gP, 256, 0, stream>>>(x, part, Wv1, bv1, Ws1, bs1,
                                   Wq2, bq2, Wk2, bk2, Wv2, bv2, Ws2, bs2,
                                   q2, kv2, hs2, N);
    l2r_k<<<NB * S_SLICES, 256, 0, stream>>>(q2, kv2, recs, bucketBase, part, N);
    out2x_k<<<gP, 256, 0, stream>>>(part, hs2, (float*)d_out, N);
}